// Round 3
// baseline (1550.715 us; speedup 1.0000x reference)
//
#include <hip/hip_runtime.h>
#include <hip/hip_bf16.h>

typedef __bf16 bf16;
typedef __bf16 bf16x8 __attribute__((ext_vector_type(8)));
typedef __bf16 bf16x4v __attribute__((ext_vector_type(4)));
typedef float f32x4 __attribute__((ext_vector_type(4)));

#define NN 100000
#define NE 600000

static __device__ __forceinline__ float silu_f(float v) {
    return v / (1.f + __expf(-v));
}

// flags[0] = 1 if float tensors are bf16, 0 if fp32
// flags[1] = 1 if edge_index is int64, 0 if int32
__global__ void k_probe(const void* __restrict__ gamma,
                        const void* __restrict__ eidx,
                        int* __restrict__ flags) {
    unsigned g0 = ((const unsigned*)gamma)[0];
    flags[0] = (g0 == 0x3F803F80u) ? 1 : 0;
    const int* e32 = (const int*)eidx;
    int is64 = 1;
    for (int k = 1; k < 64; k += 2)
        if (e32[k] != 0) is64 = 0;
    flags[1] = is64;
}

static __device__ __forceinline__ float load_f(const void* p, long i, int isbf) {
    return isbf ? (float)((const bf16*)p)[i] : ((const float*)p)[i];
}

static __device__ __forceinline__ bf16x8 load_row8(const void* p, long off, int isbf) {
    if (isbf) return *(const bf16x8*)((const bf16*)p + off);
    const float* f = (const float*)p + off;
    f32x4 f0 = *(const f32x4*)f;
    f32x4 f1 = *(const f32x4*)(f + 4);
    bf16x8 r;
#pragma unroll
    for (int t = 0; t < 4; t++) { r[t] = (bf16)f0[t]; r[t + 4] = (bf16)f1[t]; }
    return r;
}

// ---- transpose W1 (256x256) -> w1t[n][k] bf16, W2 (256x128) -> w2t[n][k] bf16 ----
__global__ __launch_bounds__(256) void k_transpose(const void* __restrict__ W1,
                                                   const void* __restrict__ W2,
                                                   bf16* __restrict__ w1t,
                                                   bf16* __restrict__ w2t,
                                                   const int* __restrict__ flags) {
    int isbf = flags[0];
    int tid = blockIdx.x * 256 + threadIdx.x;
    if (tid < 256 * 256) {
        int k = tid >> 8, n = tid & 255;
        w1t[n * 256 + k] = (bf16)load_f(W1, tid, isbf);
    } else if (tid < 256 * 256 + 256 * 128) {
        int t = tid - 256 * 256;
        int k = t >> 7, n = t & 127;
        w2t[n * 256 + k] = (bf16)load_f(W2, t, isbf);
    }
}

// ---- scatter-add edge_attr rows onto agg (fp32 atomics) ----
// 32 threads per edge, 4 dims/thread
__global__ __launch_bounds__(256) void k_scatter(const void* __restrict__ eidx,
                                                 const void* __restrict__ eattr,
                                                 float* __restrict__ agg,
                                                 const int* __restrict__ flags) {
    int isbf = flags[0], is64 = flags[1];
    int gid = blockIdx.x * 256 + threadIdx.x;
    int e = gid >> 5;
    if (e >= NE) return;
    int c = (gid & 31) << 2;
    long dst = is64 ? (long)((const long long*)eidx)[e]
                    : (long)((const int*)eidx)[e];
    float v0, v1, v2, v3;
    if (isbf) {
        bf16x4v v = *(const bf16x4v*)((const bf16*)eattr + (long)e * 128 + c);
        v0 = (float)v[0]; v1 = (float)v[1]; v2 = (float)v[2]; v3 = (float)v[3];
    } else {
        f32x4 v = *(const f32x4*)((const float*)eattr + (long)e * 128 + c);
        v0 = v[0]; v1 = v[1]; v2 = v[2]; v3 = v[3];
    }
    float* p = agg + dst * 128 + c;
    unsafeAtomicAdd(p + 0, v0);
    unsafeAtomicAdd(p + 1, v1);
    unsafeAtomicAdd(p + 2, v2);
    unsafeAtomicAdd(p + 3, v3);
}

// ---- fused MLP: h1 = silu([x|agg]@W1+b1) (LDS), out = LN(h1@W2+b2)*g+b + x ----
// block = 256 thr (4 waves, each owns 32 rows), tile 128 rows, grid = 782
// h1 tile in LDS (64 KB), XOR-swizzled in 8-col groups: elem (r,c) at
// r*256 + ((c/8) ^ (r&31))*8 + (c&7)
__global__ __launch_bounds__(256) void k_mlp(const void* __restrict__ x,
                                             const float* __restrict__ agg,
                                             const bf16* __restrict__ w1t,
                                             const void* __restrict__ b1,
                                             const bf16* __restrict__ w2t,
                                             const void* __restrict__ b2,
                                             const void* __restrict__ gamma,
                                             const void* __restrict__ beta,
                                             void* __restrict__ out,
                                             const int* __restrict__ flags) {
    __shared__ bf16 h1s[128 * 256];  // 64 KB
    const int isbf = flags[0];
    const int tid = threadIdx.x;
    const int wave = tid >> 6, lane = tid & 63;
    const int l15 = lane & 15, quad = lane >> 4;
    const int kq = quad * 8;
    const long row0 = (long)blockIdx.x * 128;
    const int wrow = wave * 32;

    int arow[2];
#pragma unroll
    for (int i = 0; i < 2; i++) {
        long r = row0 + wrow + i * 16 + l15;
        arow[i] = (r < NN) ? (int)r : (NN - 1);
    }

    // preload A fragments: k 0..127 from x, k 128..255 from agg (fp32->bf16)
    bf16x8 ax[2][4], ag[2][4];
#pragma unroll
    for (int i = 0; i < 2; i++) {
#pragma unroll
        for (int kc = 0; kc < 4; kc++) {
            ax[i][kc] = load_row8(x, (long)arow[i] * 128 + kc * 32 + kq, isbf);
            const float* p = agg + (long)arow[i] * 128 + kc * 32 + kq;
            f32x4 f0 = *(const f32x4*)p;
            f32x4 f1 = *(const f32x4*)(p + 4);
#pragma unroll
            for (int t = 0; t < 4; t++) {
                ag[i][kc][t] = (bf16)f0[t];
                ag[i][kc][t + 4] = (bf16)f1[t];
            }
        }
    }

    // ---- stage 1: h1 tile, 4 column-chunks of 64 ----
#pragma unroll
    for (int jc = 0; jc < 4; jc++) {
        f32x4 acc[2][4] = {};
#pragma unroll
        for (int kc = 0; kc < 4; kc++) {  // k in [0,128): A = x
            bf16x8 b[4];
#pragma unroll
            for (int j = 0; j < 4; j++)
                b[j] = *(const bf16x8*)(w1t + (long)(jc * 64 + j * 16 + l15) * 256 + kc * 32 + kq);
#pragma unroll
            for (int i = 0; i < 2; i++)
#pragma unroll
                for (int j = 0; j < 4; j++)
                    acc[i][j] = __builtin_amdgcn_mfma_f32_16x16x32_bf16(ax[i][kc], b[j], acc[i][j], 0, 0, 0);
        }
#pragma unroll
        for (int kc = 0; kc < 4; kc++) {  // k in [128,256): A = agg
            bf16x8 b[4];
#pragma unroll
            for (int j = 0; j < 4; j++)
                b[j] = *(const bf16x8*)(w1t + (long)(jc * 64 + j * 16 + l15) * 256 + 128 + kc * 32 + kq);
#pragma unroll
            for (int i = 0; i < 2; i++)
#pragma unroll
                for (int j = 0; j < 4; j++)
                    acc[i][j] = __builtin_amdgcn_mfma_f32_16x16x32_bf16(ag[i][kc], b[j], acc[i][j], 0, 0, 0);
        }
        // epilogue: bias + SiLU -> LDS (swizzled)
        float bias[4];
#pragma unroll
        for (int j = 0; j < 4; j++) bias[j] = load_f(b1, jc * 64 + j * 16 + l15, isbf);
#pragma unroll
        for (int i = 0; i < 2; i++) {
#pragma unroll
            for (int r = 0; r < 4; r++) {
                int lr = wrow + i * 16 + quad * 4 + r;
#pragma unroll
                for (int j = 0; j < 4; j++) {
                    int c = jc * 64 + j * 16 + l15;
                    int g = c >> 3, o = c & 7;
                    h1s[lr * 256 + ((g ^ (lr & 31)) << 3) + o] =
                        (bf16)silu_f(acc[i][j][r] + bias[j]);
                }
            }
        }
    }
    __syncthreads();

    // ---- stage 2: out = LN(h1 @ W2 + b2)*gamma + beta + x ----
    f32x4 acc2[2][8] = {};
#pragma unroll
    for (int kc = 0; kc < 8; kc++) {
        bf16x8 a[2], b[8];
#pragma unroll
        for (int i = 0; i < 2; i++) {
            int lr = wrow + i * 16 + l15;
            int g = kc * 4 + quad;
            a[i] = *(const bf16x8*)(h1s + lr * 256 + ((g ^ (lr & 31)) << 3));
        }
#pragma unroll
        for (int j = 0; j < 8; j++)
            b[j] = *(const bf16x8*)(w2t + (long)(j * 16 + l15) * 256 + kc * 32 + kq);
#pragma unroll
        for (int i = 0; i < 2; i++)
#pragma unroll
            for (int j = 0; j < 8; j++)
                acc2[i][j] = __builtin_amdgcn_mfma_f32_16x16x32_bf16(a[i], b[j], acc2[i][j], 0, 0, 0);
    }

    float b2c[8], gm[8], bt[8];
#pragma unroll
    for (int j = 0; j < 8; j++) {
        int c = j * 16 + l15;
        b2c[j] = load_f(b2, c, isbf);
        gm[j] = load_f(gamma, c, isbf);
        bt[j] = load_f(beta, c, isbf);
    }

#pragma unroll
    for (int i = 0; i < 2; i++) {
#pragma unroll
        for (int r = 0; r < 4; r++) {
            long row = row0 + wrow + i * 16 + quad * 4 + r;
            float v[8], s = 0.f, s2 = 0.f;
#pragma unroll
            for (int j = 0; j < 8; j++) {
                v[j] = acc2[i][j][r] + b2c[j];
                s += v[j];
                s2 += v[j] * v[j];
            }
#pragma unroll
            for (int m = 1; m < 16; m <<= 1) {
                s += __shfl_xor(s, m, 64);
                s2 += __shfl_xor(s2, m, 64);
            }
            float mu = s * (1.f / 128.f);
            float var = s2 * (1.f / 128.f) - mu * mu;
            float rstd = rsqrtf(var + 1e-5f);
            if (row < NN) {
#pragma unroll
                for (int j = 0; j < 8; j++) {
                    int c = j * 16 + l15;
                    float o = (v[j] - mu) * rstd * gm[j] + bt[j] + load_f(x, row * 128 + c, isbf);
                    if (isbf) ((bf16*)out)[row * 128 + c] = (bf16)o;
                    else      ((float*)out)[row * 128 + c] = o;
                }
            }
        }
    }
}

extern "C" void kernel_launch(void* const* d_in, const int* in_sizes, int n_in,
                              void* d_out, int out_size, void* d_ws, size_t ws_size,
                              hipStream_t stream) {
    const void* x     = d_in[0];
    const void* eidx  = d_in[1];   // edge_index flat [2][NE]; row 0 = dest
    const void* eattr = d_in[2];
    const void* W1    = d_in[3];
    const void* b1    = d_in[4];
    const void* W2    = d_in[5];
    const void* b2    = d_in[6];
    const void* gamma = d_in[7];
    const void* beta  = d_in[8];

    // workspace layout (total 51,462,144 B):
    //   [0, 128KB)            w1t bf16 [256][256]
    //   [128KB, 192KB)        w2t bf16 [128][256]
    //   [192KB, 192KB+64)     flags (2 ints)
    //   [256KB, +51.2MB)      agg fp32 [NN][128]
    char* ws = (char*)d_ws;
    bf16*  w1t   = (bf16*)ws;
    bf16*  w2t   = (bf16*)(ws + 131072);
    int*   flags = (int*)(ws + 196608);
    float* agg   = (float*)(ws + 262144);

    k_probe<<<1, 1, 0, stream>>>(gamma, eidx, flags);
    hipMemsetAsync(agg, 0, (size_t)NN * 128 * 4, stream);
    k_transpose<<<384, 256, 0, stream>>>(W1, W2, w1t, w2t, flags);
    k_scatter<<<(NE * 32) / 256, 256, 0, stream>>>(eidx, eattr, agg, flags);
    k_mlp<<<782, 256, 0, stream>>>(x, agg, w1t, b1, w2t, b2, gamma, beta, d_out, flags);
}